// Round 1
// baseline (87.315 us; speedup 1.0000x reference)
//
#include <hip/hip_runtime.h>

#define FDIM 1024
#define FD4 256   // float4 (and quantized dwords) per row
#define BDIM 512
#define PDIM 512

__device__ __forceinline__ unsigned sad8(unsigned a, unsigned b, unsigned c) {
  return __builtin_amdgcn_sad_u8(a, b, c);  // sum_{4 bytes} |a_i - b_i| + c
}

__device__ __forceinline__ unsigned quant4(float4 v) {
  float s0 = 1.f / (1.f + __expf(-v.x));
  float s1 = 1.f / (1.f + __expf(-v.y));
  float s2 = 1.f / (1.f + __expf(-v.z));
  float s3 = 1.f / (1.f + __expf(-v.w));
  unsigned q0 = (unsigned)(s0 * 255.f + 0.5f);
  unsigned q1 = (unsigned)(s1 * 255.f + 0.5f);
  unsigned q2 = (unsigned)(s2 * 255.f + 0.5f);
  unsigned q3 = (unsigned)(s3 * 255.f + 0.5f);
  return q0 | (q1 << 8) | (q2 << 16) | (q3 << 24);
}

// One fused kernel: each block owns 64 b-rows x 8 p-cols.
// Phase A: quantize the block's 8 w rows -> LDS wqs[8][256] (coalesced loads,
//          lane-contiguous LDS writes).
// Phase B: quantize the block's 64 x rows -> LDS xT[dword][b] transposed.
//          Stride-65 padding (65 = 1 mod 32) makes both the stride-65 write
//          and the lane-contiguous read conflict-free.
// Phase C: pull each thread's 64-dword x slice into VGPRs; slice byte-sums.
// Phase D: 8 p-cols x 64 SADs from regs vs LDS-broadcast w (uniform addr).
// Phase E: cross-wave reduce + Tversky ratio + bias.
__global__ __launch_bounds__(256) void tversky_fused(
    const float* __restrict__ x, const float* __restrict__ w,
    const float* __restrict__ bias, const float* __restrict__ alphap,
    const float* __restrict__ betap, float* __restrict__ out) {
  __shared__ unsigned xT[FD4][65];                 // 66,560 B
  __shared__ __align__(16) unsigned wqs[8][FD4];   //  8,192 B
  __shared__ unsigned short part[4][8][64];        //  4,096 B (D <= 65280)
  __shared__ unsigned short sxp[4][64];            //    512 B (slice Sx <= 65280)
  __shared__ unsigned swsum[8];

  const int tid = threadIdx.x;
  const int lane = tid & 63;
  const int wv = __builtin_amdgcn_readfirstlane(tid >> 6);  // F-slice, uniform
  const int r0 = blockIdx.y * 64;  // b-row base
  const int c0 = blockIdx.x * 8;   // p-col base

  if (tid < 8) swsum[tid] = 0;  // covered by the phase A/B barrier

  const float4* __restrict__ xf4 = (const float4*)x;
  const float4* __restrict__ wf4 = (const float4*)w;

  // Phase A: 8 w rows, one full row per iteration (256 float4, coalesced).
#pragma unroll
  for (int j = 0; j < 8; ++j) {
    wqs[j][tid] = quant4(wf4[(size_t)(c0 + j) * FD4 + tid]);
  }

  // Phase B: 64 x rows; unroll 2 keeps <=16 float4 of staging in flight.
#pragma unroll 2
  for (int ii = 0; ii < 8; ++ii) {
    float4 v[8];
#pragma unroll
    for (int j = 0; j < 8; ++j)
      v[j] = xf4[(size_t)(r0 + ii * 8 + j) * FD4 + tid];
#pragma unroll
    for (int j = 0; j < 8; ++j) xT[tid][ii * 8 + j] = quant4(v[j]);
  }
  __syncthreads();

  // Phase C: x slice to registers (lane-contiguous LDS reads, conflict-free)
  unsigned xv[64];
#pragma unroll
  for (int k = 0; k < 64; ++k) xv[k] = xT[wv * 64 + k][lane];

  unsigned sx = 0;
#pragma unroll
  for (int k = 0; k < 64; ++k) sx = sad8(xv[k], 0u, sx);
  sxp[wv][lane] = (unsigned short)sx;

  // Sw for the block's 8 w rows (from LDS; 32 threads per row).
  {
    const int wrow = tid >> 5;
    const int seg = tid & 31;
    const uint4* wp = (const uint4*)&wqs[wrow][seg * 8];
    const uint4 q0 = wp[0], q1 = wp[1];
    unsigned s = 0;
    s = sad8(q0.x, 0u, s); s = sad8(q0.y, 0u, s);
    s = sad8(q0.z, 0u, s); s = sad8(q0.w, 0u, s);
    s = sad8(q1.x, 0u, s); s = sad8(q1.y, 0u, s);
    s = sad8(q1.z, 0u, s); s = sad8(q1.w, 0u, s);
    atomicAdd(&swsum[wrow], s);
  }

  // Phase D: 8 cols x 64 SADs, 4 chains; w via uniform LDS reads (broadcast).
  for (int pp = 0; pp < 8; ++pp) {
    unsigned a0 = 0, a1 = 0, a2 = 0, a3 = 0;
#pragma unroll
    for (int j = 0; j < 16; ++j) {
      const uint4 q = *(const uint4*)&wqs[pp][wv * 64 + 4 * j];
      a0 = sad8(xv[4 * j + 0], q.x, a0);
      a1 = sad8(xv[4 * j + 1], q.y, a1);
      a2 = sad8(xv[4 * j + 2], q.z, a2);
      a3 = sad8(xv[4 * j + 3], q.w, a3);
    }
    part[wv][pp][lane] = (unsigned short)(a0 + a1 + a2 + a3);
  }
  __syncthreads();

  // Phase E: reduce across the 4 F-slices and emit.
  const float alpha = alphap[0];
  const float beta = betap[0];
#pragma unroll
  for (int id = tid; id < 512; id += 256) {
    const int row = id >> 3;
    const int pp = id & 7;
    const unsigned D = (unsigned)part[0][pp][row] + part[1][pp][row] +
                       part[2][pp][row] + part[3][pp][row];
    const unsigned Sxi = (unsigned)sxp[0][row] + sxp[1][row] +
                         sxp[2][row] + sxp[3][row];
    const unsigned Swi = swsum[pp];
    const float fSx = (float)Sxi;
    const float fSw = (float)Swi;
    const float I = 0.5f * (fSx + fSw - (float)D);
    // All terms in int units (255x real); eps scales by 255.
    const float denom = I + alpha * (fSx - I) + beta * (fSw - I) + 255.0f * 1e-8f;
    out[(r0 + row) * PDIM + (c0 + pp)] = I / denom + bias[c0 + pp];
  }
}

extern "C" void kernel_launch(void* const* d_in, const int* in_sizes, int n_in,
                              void* d_out, int out_size, void* d_ws, size_t ws_size,
                              hipStream_t stream) {
  const float* x = (const float*)d_in[0];
  const float* w = (const float*)d_in[1];
  const float* bias = (const float*)d_in[2];
  const float* alpha = (const float*)d_in[3];
  const float* beta = (const float*)d_in[4];
  float* out = (float*)d_out;
  (void)in_sizes; (void)n_in; (void)d_ws; (void)ws_size;

  tversky_fused<<<dim3(PDIM / 8, BDIM / 64), dim3(256), 0, stream>>>(
      x, w, bias, alpha, beta, out);
}